// Round 1
// baseline (8419.938 us; speedup 1.0000x reference)
//
#include <hip/hip_runtime.h>

// ---------------------------------------------------------------------------
// Problem constants: B=8, S=128, IN=512, D=1024, E=4, NH=16, DH=64
// tokens N = B*S = 1024
// ---------------------------------------------------------------------------

// ---------------- router: logits = x@rw + rb, softmax over E=4 -------------
__global__ __launch_bounds__(64) void router_kernel(
    const float* __restrict__ x, const float* __restrict__ rw,
    const float* __restrict__ rb, float* __restrict__ router)
{
    int token = blockIdx.x;          // 0..1023
    int lane = threadIdx.x;          // 0..63
    float a0 = 0.f, a1 = 0.f, a2 = 0.f, a3 = 0.f;
    const float* xp = x + (long)token * 512;
    for (int i = lane; i < 512; i += 64) {
        float xv = xp[i];
        const float* w = rw + (long)i * 4;
        a0 += xv * w[0]; a1 += xv * w[1]; a2 += xv * w[2]; a3 += xv * w[3];
    }
    #pragma unroll
    for (int off = 32; off; off >>= 1) {
        a0 += __shfl_down(a0, off);
        a1 += __shfl_down(a1, off);
        a2 += __shfl_down(a2, off);
        a3 += __shfl_down(a3, off);
    }
    if (lane == 0) {
        a0 += rb[0]; a1 += rb[1]; a2 += rb[2]; a3 += rb[3];
        float m = fmaxf(fmaxf(a0, a1), fmaxf(a2, a3));
        float e0 = __expf(a0 - m), e1 = __expf(a1 - m);
        float e2 = __expf(a2 - m), e3 = __expf(a3 - m);
        float inv = 1.f / (e0 + e1 + e2 + e3);
        float4 r = make_float4(e0 * inv, e1 * inv, e2 * inv, e3 * inv);
        *reinterpret_cast<float4*>(&router[token * 4]) = r;
    }
}

// ---------------- generic batched fp32 GEMM: C = act(A@W + bias) [*mul] ----
// A: [M=1024, K] row-major (per-batch stride sAe; 0 = shared)
// W: [K, N] row-major, stride sWe per batch (blockIdx.z)
// act: 0 none, 1 relu, 2 sigmoid, 3 tanh; mulin optional elementwise multiplier
__global__ __launch_bounds__(256) void gemm_f32(
    const float* __restrict__ A, const float* __restrict__ W,
    const float* __restrict__ bias, const float* __restrict__ mulin,
    float* __restrict__ C, int N, int K,
    long sAe, long sWe, long sBe, long sMe, long sCe, int act)
{
    __shared__ __align__(16) float As[8][128];
    __shared__ __align__(16) float Bs[8][128];
    int e = blockIdx.z;
    A += (long)e * sAe; W += (long)e * sWe; bias += (long)e * sBe; C += (long)e * sCe;
    int tid = threadIdx.x;
    int row0 = blockIdx.y * 128, col0 = blockIdx.x * 128;
    int ty = tid >> 4, tx = tid & 15;
    int arow = tid >> 1, akq = (tid & 1) * 4;
    int bk = tid >> 5, bn = (tid & 31) * 4;
    float acc[8][8] = {};
    const float* Ap = A + (long)(row0 + arow) * K + akq;
    const float* Wp = W + (long)bk * N + col0 + bn;
    for (int k0 = 0; k0 < K; k0 += 8) {
        float4 av = *reinterpret_cast<const float4*>(Ap + k0);
        float4 bv = *reinterpret_cast<const float4*>(Wp + (long)k0 * N);
        As[akq + 0][arow] = av.x; As[akq + 1][arow] = av.y;
        As[akq + 2][arow] = av.z; As[akq + 3][arow] = av.w;
        *reinterpret_cast<float4*>(&Bs[bk][bn]) = bv;
        __syncthreads();
        #pragma unroll
        for (int k = 0; k < 8; ++k) {
            float a[8], b[8];
            *reinterpret_cast<float4*>(&a[0]) = *reinterpret_cast<const float4*>(&As[k][ty * 8]);
            *reinterpret_cast<float4*>(&a[4]) = *reinterpret_cast<const float4*>(&As[k][ty * 8 + 4]);
            *reinterpret_cast<float4*>(&b[0]) = *reinterpret_cast<const float4*>(&Bs[k][tx * 8]);
            *reinterpret_cast<float4*>(&b[4]) = *reinterpret_cast<const float4*>(&Bs[k][tx * 8 + 4]);
            #pragma unroll
            for (int i = 0; i < 8; ++i)
                #pragma unroll
                for (int j = 0; j < 8; ++j)
                    acc[i][j] = fmaf(a[i], b[j], acc[i][j]);
        }
        __syncthreads();
    }
    #pragma unroll
    for (int i = 0; i < 8; ++i) {
        long r = row0 + ty * 8 + i;
        #pragma unroll
        for (int jj = 0; jj < 2; ++jj) {
            float4 o;
            float* op = &o.x;
            #pragma unroll
            for (int j = 0; j < 4; ++j) {
                int c = col0 + tx * 8 + jj * 4 + j;
                float v = acc[i][jj * 4 + j] + bias[c];
                if (act == 1) v = fmaxf(v, 0.f);
                else if (act == 2) v = 1.f / (1.f + __expf(-v));
                else if (act == 3) v = tanhf(v);
                if (mulin) v *= mulin[(long)e * sMe + r * (long)N + c];
                op[j] = v;
            }
            *reinterpret_cast<float4*>(&C[r * (long)N + col0 + tx * 8 + jj * 4]) = o;
        }
    }
}

// ---------------- in-place LayerNorm over last dim (per expert g/beta) -----
template <int DIM>
__global__ __launch_bounds__(256) void ln_kernel(
    float* __restrict__ buf, const float* __restrict__ g,
    const float* __restrict__ beta)
{
    constexpr int PT = DIM / 256;
    __shared__ float sbuf[4];
    int row = blockIdx.x;            // E*1024 rows, 1024 per expert
    int e = row >> 10;
    float* p = buf + (long)row * DIM;
    const float* gp = g + (long)e * DIM;
    const float* bp = beta + (long)e * DIM;
    int tid = threadIdx.x;
    float v[PT];
    float s = 0.f;
    #pragma unroll
    for (int i = 0; i < PT; ++i) { v[i] = p[tid + i * 256]; s += v[i]; }
    #pragma unroll
    for (int off = 32; off; off >>= 1) s += __shfl_down(s, off);
    if ((tid & 63) == 0) sbuf[tid >> 6] = s;
    __syncthreads();
    float mean = (sbuf[0] + sbuf[1] + sbuf[2] + sbuf[3]) / (float)DIM;
    __syncthreads();
    float vs = 0.f;
    #pragma unroll
    for (int i = 0; i < PT; ++i) { float d = v[i] - mean; vs += d * d; }
    #pragma unroll
    for (int off = 32; off; off >>= 1) vs += __shfl_down(vs, off);
    if ((tid & 63) == 0) sbuf[tid >> 6] = vs;
    __syncthreads();
    float var = (sbuf[0] + sbuf[1] + sbuf[2] + sbuf[3]) / (float)DIM;
    float rstd = rsqrtf(var + 1e-5f);
    #pragma unroll
    for (int i = 0; i < PT; ++i)
        p[tid + i * 256] = (v[i] - mean) * rstd * gp[tid + i * 256] + bp[tid + i * 256];
}

// ---------------- fused attention: one block per (e,b,head) ----------------
// qkv: [E,1024,3072] (q|k|v); o: [E,1024,1024]
__global__ __launch_bounds__(128) void attn_kernel(
    const float* __restrict__ qkv, float* __restrict__ o)
{
    __shared__ __align__(16) float Ks[128][64];
    __shared__ __align__(16) float Vs[128][64];
    int id = blockIdx.x;
    int hd = id & 15, b = (id >> 4) & 7, e = id >> 7;
    int tid = threadIdx.x;           // 0..127, one q row each
    const long base = ((long)e * 1024 + b * 128) * 3072 + hd * 64;
    #pragma unroll
    for (int c = 0; c < 16; ++c) {
        int idx = c * 128 + tid;
        int row = idx >> 4, f4 = (idx & 15) * 4;
        *reinterpret_cast<float4*>(&Ks[row][f4]) =
            *reinterpret_cast<const float4*>(&qkv[base + (long)row * 3072 + 1024 + f4]);
        *reinterpret_cast<float4*>(&Vs[row][f4]) =
            *reinterpret_cast<const float4*>(&qkv[base + (long)row * 3072 + 2048 + f4]);
    }
    __syncthreads();
    float q[64];
    #pragma unroll
    for (int f = 0; f < 16; ++f)
        *reinterpret_cast<float4*>(&q[f * 4]) =
            *reinterpret_cast<const float4*>(&qkv[base + (long)tid * 3072 + f * 4]);
    float m = -__builtin_huge_valf(), l = 0.f;
    float oa[64];
    #pragma unroll
    for (int d = 0; d < 64; ++d) oa[d] = 0.f;
    for (int j = 0; j < 128; ++j) {
        float s = 0.f;
        #pragma unroll
        for (int d = 0; d < 64; ++d) s = fmaf(q[d], Ks[j][d], s);
        s *= 0.125f;                 // 1/sqrt(DH=64)
        float mn = fmaxf(m, s);
        float corr = __expf(m - mn);
        float pj = __expf(s - mn);
        l = l * corr + pj;
        #pragma unroll
        for (int d = 0; d < 64; ++d) oa[d] = oa[d] * corr + pj * Vs[j][d];
        m = mn;
    }
    float inv = 1.f / l;
    float* op = o + ((long)e * 1024 + b * 128 + tid) * 1024 + hd * 64;
    #pragma unroll
    for (int f = 0; f < 16; ++f) {
        float4 t = make_float4(oa[f * 4] * inv, oa[f * 4 + 1] * inv,
                               oa[f * 4 + 2] * inv, oa[f * 4 + 3] * inv);
        *reinterpret_cast<float4*>(&op[f * 4]) = t;
    }
}

// ---------------- LSTM one time step, all (e,dir) chains -------------------
// pre: [8 ed][1024 token][4096] (x@Wi+b, token = b*128 + t_orig)
// hstate: double-buffered [2][8 ed][8 b][1024]; cstate: [8 ed][8 b][1024]
// memb: [E][B][128][2048] output (fwd at [0:1024], bwd at [1024:2048])
__global__ __launch_bounds__(256) void lstm_step(
    const float* __restrict__ pre, const float* __restrict__ whf,
    const float* __restrict__ whb, float* __restrict__ hstate,
    float* __restrict__ cstate, float* __restrict__ memb, int s)
{
    __shared__ float hs[8][1032];                 // +8 pad: conflict-free b-spread
    __shared__ __align__(16) float zgs[2][4][8][16];
    int cb = blockIdx.x;       // 0..63 : 16 h-columns each
    int ed = blockIdx.y;       // 0..7  : e*2 + dir
    int e = ed >> 1, dir = ed & 1;
    int t = dir ? (127 - s) : s;
    const float* Wh = (dir ? whb : whf) + (long)e * 1024 * 4096;
    const float* hin = hstate + (long)(s & 1) * 65536 + (long)ed * 8192;
    float* hout = hstate + (long)((s & 1) ^ 1) * 65536 + (long)ed * 8192;
    int tid = threadIdx.x;
    // stage h state for all 8 batches (32KB)
    #pragma unroll
    for (int i = 0; i < 8; ++i) {
        int idx = i * 256 + tid;
        int b = idx >> 8, k4 = (idx & 255) * 4;
        float4 v = *reinterpret_cast<const float4*>(&hin[b * 1024 + k4]);
        hs[b][k4 + 0] = v.x; hs[b][k4 + 1] = v.y;
        hs[b][k4 + 2] = v.z; hs[b][k4 + 3] = v.w;
    }
    __syncthreads();
    {
        int c4 = tid & 3, g = (tid >> 2) & 3, b = (tid >> 4) & 7, kh = tid >> 7;
        int colg = g * 1024 + cb * 16 + c4 * 4;
        const float* wp = Wh + colg + (long)kh * 512 * 4096;
        const float* hrow = &hs[b][kh * 512];
        float4 acc = make_float4(0.f, 0.f, 0.f, 0.f);
        #pragma unroll 8
        for (int k = 0; k < 512; ++k) {
            float hv = hrow[k];
            float4 w = *reinterpret_cast<const float4*>(&wp[(long)k * 4096]);
            acc.x = fmaf(hv, w.x, acc.x);
            acc.y = fmaf(hv, w.y, acc.y);
            acc.z = fmaf(hv, w.z, acc.z);
            acc.w = fmaf(hv, w.w, acc.w);
        }
        *reinterpret_cast<float4*>(&zgs[kh][g][b][c4 * 4]) = acc;
    }
    __syncthreads();
    if (tid < 128) {
        int col = tid & 15, b2 = tid >> 4;
        int hcol = cb * 16 + col;
        const float* prow = &pre[((long)ed * 1024 + b2 * 128 + t) * 4096];
        float zi = zgs[0][0][b2][col] + zgs[1][0][b2][col] + prow[hcol];
        float zf = zgs[0][1][b2][col] + zgs[1][1][b2][col] + prow[1024 + hcol];
        float zg = zgs[0][2][b2][col] + zgs[1][2][b2][col] + prow[2048 + hcol];
        float zo = zgs[0][3][b2][col] + zgs[1][3][b2][col] + prow[3072 + hcol];
        long ci = (long)ed * 8192 + b2 * 1024 + hcol;
        float c = cstate[ci];
        float ig = 1.f / (1.f + __expf(-zi));
        float fg = 1.f / (1.f + __expf(-zf));
        float gg = tanhf(zg);
        float og = 1.f / (1.f + __expf(-zo));
        c = fg * c + ig * gg;
        float h = og * tanhf(c);
        cstate[ci] = c;
        hout[b2 * 1024 + hcol] = h;
        memb[(((long)e * 8 + b2) * 128 + t) * 2048 + dir * 1024 + hcol] = h;
    }
}

// ---------------- final routing combine ------------------------------------
// outs: [E][1024][512]; router: [1024][4]; out: [1024][512]
__global__ __launch_bounds__(256) void combine_kernel(
    const float* __restrict__ outs, const float* __restrict__ router,
    float* __restrict__ out)
{
    int idx = blockIdx.x * 256 + threadIdx.x;    // float4 index, < 131072
    int token = idx >> 7, q = (idx & 127) * 4;
    float4 r = *reinterpret_cast<const float4*>(&router[token * 4]);
    const float* bp = outs + (long)token * 512 + q;
    float4 v0 = *reinterpret_cast<const float4*>(bp);
    float4 v1 = *reinterpret_cast<const float4*>(bp + 524288);
    float4 v2 = *reinterpret_cast<const float4*>(bp + 1048576);
    float4 v3 = *reinterpret_cast<const float4*>(bp + 1572864);
    float4 a;
    a.x = r.x * v0.x + r.y * v1.x + r.z * v2.x + r.w * v3.x;
    a.y = r.x * v0.y + r.y * v1.y + r.z * v2.y + r.w * v3.y;
    a.z = r.x * v0.z + r.y * v1.z + r.z * v2.z + r.w * v3.z;
    a.w = r.x * v0.w + r.y * v1.w + r.z * v2.w + r.w * v3.w;
    *reinterpret_cast<float4*>(&out[(long)token * 512 + q]) = a;
}

extern "C" void kernel_launch(void* const* d_in, const int* in_sizes, int n_in,
                              void* d_out, int out_size, void* d_ws, size_t ws_size,
                              hipStream_t stream)
{
    (void)in_sizes; (void)n_in; (void)out_size; (void)ws_size;
    const float* x        = (const float*)d_in[0];
    const float* router_w = (const float*)d_in[1];
    const float* router_b = (const float*)d_in[2];
    const float* enc_w1   = (const float*)d_in[3];
    const float* enc_b1   = (const float*)d_in[4];
    const float* enc_w2   = (const float*)d_in[5];
    const float* enc_b2   = (const float*)d_in[6];
    const float* enc_g    = (const float*)d_in[7];
    const float* enc_beta = (const float*)d_in[8];
    const float* aiw      = (const float*)d_in[9];
    const float* aib      = (const float*)d_in[10];
    const float* aow      = (const float*)d_in[11];
    const float* aob      = (const float*)d_in[12];
    const float* wif      = (const float*)d_in[13];
    const float* whf      = (const float*)d_in[14];
    const float* bf       = (const float*)d_in[15];
    const float* wib      = (const float*)d_in[16];
    const float* whb      = (const float*)d_in[17];
    const float* bb       = (const float*)d_in[18];
    const float* sw1      = (const float*)d_in[19];
    const float* sb1      = (const float*)d_in[20];
    const float* sw2      = (const float*)d_in[21];
    const float* sb2      = (const float*)d_in[22];
    const float* tw1      = (const float*)d_in[23];
    const float* tb1      = (const float*)d_in[24];
    const float* tw2      = (const float*)d_in[25];
    const float* tb2      = (const float*)d_in[26];
    const float* dw1      = (const float*)d_in[27];
    const float* db1      = (const float*)d_in[28];
    const float* dw2      = (const float*)d_in[29];
    const float* db2      = (const float*)d_in[30];
    const float* dg       = (const float*)d_in[31];
    const float* dbeta    = (const float*)d_in[32];
    float* out = (float*)d_out;

    const long M1 = 1024L * 1024L;
    float* ws     = (float*)d_ws;
    float* h      = ws;                 // [E,1024,1024]  (also tan-branch out)
    float* t1     = h + 4 * M1;         // [E,1024,1024]
    float* t2     = t1 + 4 * M1;        // [E,1024,1024]
    float* pre    = t2 + 4 * M1;        // [8ed,1024,4096] (also qkv [E,1024,3072])
    float* memb   = pre + 32 * M1;      // [E,8,128,2048]
    float* outs   = memb + 8 * M1;      // [E,1024,512]
    float* router = outs + 2 * M1;      // [1024,4]
    float* hstate = router + 4096;      // [2][8][8][1024]
    float* cstate = hstate + 131072;    // [8][8][1024]
    // total: 54*M1 + ~200K floats ≈ 217 MB

    hipMemsetAsync(hstate, 0, 65536 * sizeof(float), stream);   // h0 buffer only
    hipMemsetAsync(cstate, 0, 65536 * sizeof(float), stream);

    router_kernel<<<1024, 64, 0, stream>>>(x, router_w, router_b, router);

    dim3 blk(256);
    // encoder: t1 = relu(x@ew1+eb1); h = ln(t1@ew2+eb2)
    gemm_f32<<<dim3(8, 8, 4), blk, 0, stream>>>(x, enc_w1, enc_b1, nullptr, t1,
        1024, 512, 0L, 512L * 1024L, 1024L, 0L, M1, 1);
    gemm_f32<<<dim3(8, 8, 4), blk, 0, stream>>>(t1, enc_w2, enc_b2, nullptr, h,
        1024, 1024, M1, M1, 1024L, 0L, M1, 0);
    ln_kernel<1024><<<4096, 256, 0, stream>>>(h, enc_g, enc_beta);
    // attention
    gemm_f32<<<dim3(24, 8, 4), blk, 0, stream>>>(h, aiw, aib, nullptr, pre,
        3072, 1024, M1, 3 * M1, 3072L, 0L, 3 * M1, 0);
    attn_kernel<<<512, 128, 0, stream>>>(pre, t1);
    gemm_f32<<<dim3(8, 8, 4), blk, 0, stream>>>(t1, aow, aob, nullptr, h,
        1024, 1024, M1, M1, 1024L, 0L, M1, 0);
    // LSTM input projections (fwd -> pre[ed even], bwd -> pre[ed odd])
    gemm_f32<<<dim3(32, 8, 4), blk, 0, stream>>>(h, wif, bf, nullptr, pre,
        4096, 1024, M1, 4 * M1, 4096L, 0L, 8 * M1, 0);
    gemm_f32<<<dim3(32, 8, 4), blk, 0, stream>>>(h, wib, bb, nullptr, pre + 4 * M1,
        4096, 1024, M1, 4 * M1, 4096L, 0L, 8 * M1, 0);
    // recurrence: 128 sequential steps
    for (int s = 0; s < 128; ++s)
        lstm_step<<<dim3(64, 8), blk, 0, stream>>>(pre, whf, whb, hstate, cstate, memb, s);
    // gate branches: t2 = sigmoid(relu(mem@sw1)@sw2); h = tanh(relu(mem@tw1)@tw2) * t2
    gemm_f32<<<dim3(8, 8, 4), blk, 0, stream>>>(memb, sw1, sb1, nullptr, t1,
        1024, 2048, 2 * M1, 2 * M1, 1024L, 0L, M1, 1);
    gemm_f32<<<dim3(8, 8, 4), blk, 0, stream>>>(t1, sw2, sb2, nullptr, t2,
        1024, 1024, M1, M1, 1024L, 0L, M1, 2);
    gemm_f32<<<dim3(8, 8, 4), blk, 0, stream>>>(memb, tw1, tb1, nullptr, t1,
        1024, 2048, 2 * M1, 2 * M1, 1024L, 0L, M1, 1);
    gemm_f32<<<dim3(8, 8, 4), blk, 0, stream>>>(t1, tw2, tb2, t2, h,
        1024, 1024, M1, M1, 1024L, M1, M1, 3);
    // decoder: outs = ln(relu(h@dw1)@dw2)
    gemm_f32<<<dim3(8, 8, 4), blk, 0, stream>>>(h, dw1, db1, nullptr, t1,
        1024, 1024, M1, M1, 1024L, 0L, M1, 1);
    gemm_f32<<<dim3(4, 8, 4), blk, 0, stream>>>(t1, dw2, db2, nullptr, outs,
        512, 1024, M1, 512L * 1024L, 512L, 0L, 512L * 1024L, 0);
    ln_kernel<512><<<4096, 256, 0, stream>>>(outs, dg, dbeta);
    // routed combine
    combine_kernel<<<512, 256, 0, stream>>>(outs, router, out);
}

// Round 2
// 2517.075 us; speedup vs baseline: 3.3451x; 3.3451x over previous
//
#include <hip/hip_runtime.h>

// B=8, S=128, IN=512, D=1024, E=4, NH=16, DH=64; tokens N=1024
// Strategy: bf16 weights (transposed [N][K]) + MFMA 16x16x32 for all GEMMs and
// the LSTM recurrence; fp32 accumulate and fp32 gate/LN math.

typedef __attribute__((ext_vector_type(8))) short short8v;
typedef __attribute__((ext_vector_type(4))) float float4v;

__device__ __forceinline__ float bf2f(unsigned short u) {
    unsigned int x = ((unsigned int)u) << 16;
    return __builtin_bit_cast(float, x);
}
__device__ __forceinline__ unsigned short f2bf(float f) {
    unsigned int u = __builtin_bit_cast(unsigned int, f);
    u += 0x7fffu + ((u >> 16) & 1u);
    return (unsigned short)(u >> 16);
}

// ---------------- fp32 -> bf16 elementwise convert -------------------------
__global__ __launch_bounds__(256) void cvt_bf16_kernel(
    const float* __restrict__ in, unsigned short* __restrict__ out, int n4)
{
    int i = blockIdx.x * 256 + threadIdx.x;
    if (i >= n4) return;
    float4 v = *reinterpret_cast<const float4*>(&in[i * 4]);
    ushort4 o;
    o.x = f2bf(v.x); o.y = f2bf(v.y); o.z = f2bf(v.z); o.w = f2bf(v.w);
    *reinterpret_cast<ushort4*>(&out[i * 4]) = o;
}

// ---------------- W[K][N] fp32 -> Wt[N][K] bf16 (batched over E) -----------
__global__ __launch_bounds__(256) void transpose_bf16(
    const float* __restrict__ W, unsigned short* __restrict__ Wt,
    int K, int N, long sWe, long sTe)
{
    __shared__ float tile[32][33];
    int e = blockIdx.z;
    W += (long)e * sWe; Wt += (long)e * sTe;
    int k0 = blockIdx.y * 32, n0 = blockIdx.x * 32;
    int tx = threadIdx.x & 31, ty = threadIdx.x >> 5;   // ty 0..7
    #pragma unroll
    for (int i = 0; i < 32; i += 8)
        tile[ty + i][tx] = W[(long)(k0 + ty + i) * N + n0 + tx];
    __syncthreads();
    #pragma unroll
    for (int i = 0; i < 32; i += 8)
        Wt[(long)(n0 + ty + i) * K + k0 + tx] = f2bf(tile[tx][ty + i]);
}

// ---------------- router (fp32) --------------------------------------------
__global__ __launch_bounds__(64) void router_kernel(
    const float* __restrict__ x, const float* __restrict__ rw,
    const float* __restrict__ rb, float* __restrict__ router)
{
    int token = blockIdx.x;
    int lane = threadIdx.x;
    float a0 = 0.f, a1 = 0.f, a2 = 0.f, a3 = 0.f;
    const float* xp = x + (long)token * 512;
    for (int i = lane; i < 512; i += 64) {
        float xv = xp[i];
        const float* w = rw + (long)i * 4;
        a0 += xv * w[0]; a1 += xv * w[1]; a2 += xv * w[2]; a3 += xv * w[3];
    }
    #pragma unroll
    for (int off = 32; off; off >>= 1) {
        a0 += __shfl_down(a0, off); a1 += __shfl_down(a1, off);
        a2 += __shfl_down(a2, off); a3 += __shfl_down(a3, off);
    }
    if (lane == 0) {
        a0 += rb[0]; a1 += rb[1]; a2 += rb[2]; a3 += rb[3];
        float m = fmaxf(fmaxf(a0, a1), fmaxf(a2, a3));
        float e0 = __expf(a0 - m), e1 = __expf(a1 - m);
        float e2 = __expf(a2 - m), e3 = __expf(a3 - m);
        float inv = 1.f / (e0 + e1 + e2 + e3);
        *reinterpret_cast<float4*>(&router[token * 4]) =
            make_float4(e0 * inv, e1 * inv, e2 * inv, e3 * inv);
    }
}

// ---------------- MFMA bf16 GEMM: C = act(A@W + bias) [*mul] ---------------
// A [M,K] bf16 row-major (batch stride sAe), Wt [N,K] bf16 (stride sWe)
// bias fp32 (stride sBe), mul bf16 [M,N] optional (stride sMe)
// OUTBF=1 -> bf16 out, else fp32. 128x128 tile, 4 waves, BK=64.
template <int OUTBF>
__global__ __launch_bounds__(256) void gemm_bf16(
    const unsigned short* __restrict__ A, const unsigned short* __restrict__ Wt,
    const float* __restrict__ bias, const unsigned short* __restrict__ mul,
    void* __restrict__ Cv, int N, int K,
    long sAe, long sWe, long sBe, long sMe, long sCe, int act)
{
    __shared__ unsigned short As[128 * 64];
    __shared__ unsigned short Bs[128 * 64];
    int e = blockIdx.z;
    A += (long)e * sAe; Wt += (long)e * sWe; bias += (long)e * sBe;
    if (mul) mul += (long)e * sMe;
    int tid = threadIdx.x;
    int row0 = blockIdx.y * 128, col0 = blockIdx.x * 128;
    int wid = tid >> 6, lane = tid & 63;
    int wr = wid >> 1, wc = wid & 1;
    int l15 = lane & 15, l4 = lane >> 4;
    float4v acc[4][4];
    #pragma unroll
    for (int i = 0; i < 4; ++i)
        #pragma unroll
        for (int j = 0; j < 4; ++j) acc[i][j] = (float4v){0.f, 0.f, 0.f, 0.f};
    for (int k0 = 0; k0 < K; k0 += 64) {
        __syncthreads();
        #pragma unroll
        for (int i = 0; i < 4; ++i) {
            int idx = tid + 256 * i;
            int r = idx >> 3, sg = (idx & 7) * 16;        // byte seg in 128B row
            int swz = sg ^ ((r & 7) << 4);
            *reinterpret_cast<short8v*>((char*)As + r * 128 + swz) =
                *reinterpret_cast<const short8v*>(A + (long)(row0 + r) * K + k0 + (sg >> 1));
            *reinterpret_cast<short8v*>((char*)Bs + r * 128 + swz) =
                *reinterpret_cast<const short8v*>(Wt + (long)(col0 + r) * K + k0 + (sg >> 1));
        }
        __syncthreads();
        #pragma unroll
        for (int kk = 0; kk < 2; ++kk) {
            short8v af[4], bq[4];
            int bytec = kk * 64 + l4 * 16;
            #pragma unroll
            for (int m = 0; m < 4; ++m) {
                int r = wr * 64 + m * 16 + l15;
                af[m] = *reinterpret_cast<const short8v*>(
                    (char*)As + r * 128 + (bytec ^ ((r & 7) << 4)));
            }
            #pragma unroll
            for (int n = 0; n < 4; ++n) {
                int r = wc * 64 + n * 16 + l15;
                bq[n] = *reinterpret_cast<const short8v*>(
                    (char*)Bs + r * 128 + (bytec ^ ((r & 7) << 4)));
            }
            #pragma unroll
            for (int m = 0; m < 4; ++m)
                #pragma unroll
                for (int n = 0; n < 4; ++n)
                    acc[m][n] = __builtin_amdgcn_mfma_f32_16x16x32_bf16(
                        af[m], bq[n], acc[m][n], 0, 0, 0);
        }
    }
    float* Cf = (float*)Cv + (long)e * sCe;
    unsigned short* Cb = (unsigned short*)Cv + (long)e * sCe;
    #pragma unroll
    for (int n = 0; n < 4; ++n) {
        int col = col0 + wc * 64 + n * 16 + l15;
        float bia = bias[col];
        #pragma unroll
        for (int m = 0; m < 4; ++m) {
            #pragma unroll
            for (int r = 0; r < 4; ++r) {
                long row = row0 + wr * 64 + m * 16 + l4 * 4 + r;
                float v = acc[m][n][r] + bia;
                if (act == 1) v = fmaxf(v, 0.f);
                else if (act == 2) v = 1.f / (1.f + __expf(-v));
                else if (act == 3) v = tanhf(v);
                if (mul) v *= bf2f(mul[row * N + col]);
                if (OUTBF) Cb[row * N + col] = f2bf(v);
                else       Cf[row * N + col] = v;
            }
        }
    }
}

// ---------------- LayerNorm bf16 in/out (DIM=1024), per-expert g/beta ------
template <int DIM>
__global__ __launch_bounds__(256) void ln_bf16(
    unsigned short* __restrict__ buf, const float* __restrict__ g,
    const float* __restrict__ beta)
{
    constexpr int PT = DIM / 256;
    __shared__ float sbuf[4];
    int row = blockIdx.x, e = row >> 10;
    unsigned short* p = buf + (long)row * DIM;
    const float* gp = g + (long)e * DIM;
    const float* bp = beta + (long)e * DIM;
    int tid = threadIdx.x;
    float v[PT];
    ushort4 u = *reinterpret_cast<const ushort4*>(p + tid * PT);
    v[0] = bf2f(u.x); v[1] = bf2f(u.y); v[2] = bf2f(u.z); v[3] = bf2f(u.w);
    float s = v[0] + v[1] + v[2] + v[3];
    #pragma unroll
    for (int off = 32; off; off >>= 1) s += __shfl_down(s, off);
    if ((tid & 63) == 0) sbuf[tid >> 6] = s;
    __syncthreads();
    float mean = (sbuf[0] + sbuf[1] + sbuf[2] + sbuf[3]) / (float)DIM;
    __syncthreads();
    float vs = 0.f;
    #pragma unroll
    for (int i = 0; i < PT; ++i) { float d = v[i] - mean; vs += d * d; }
    #pragma unroll
    for (int off = 32; off; off >>= 1) vs += __shfl_down(vs, off);
    if ((tid & 63) == 0) sbuf[tid >> 6] = vs;
    __syncthreads();
    float var = (sbuf[0] + sbuf[1] + sbuf[2] + sbuf[3]) / (float)DIM;
    float rstd = rsqrtf(var + 1e-5f);
    ushort4 o;
    o.x = f2bf((v[0] - mean) * rstd * gp[tid * PT + 0] + bp[tid * PT + 0]);
    o.y = f2bf((v[1] - mean) * rstd * gp[tid * PT + 1] + bp[tid * PT + 1]);
    o.z = f2bf((v[2] - mean) * rstd * gp[tid * PT + 2] + bp[tid * PT + 2]);
    o.w = f2bf((v[3] - mean) * rstd * gp[tid * PT + 3] + bp[tid * PT + 3]);
    *reinterpret_cast<ushort4*>(p + tid * PT) = o;
}

// ---------------- LayerNorm fp32 in-place (DIM=512 final) ------------------
template <int DIM>
__global__ __launch_bounds__(256) void ln_kernel(
    float* __restrict__ buf, const float* __restrict__ g,
    const float* __restrict__ beta)
{
    constexpr int PT = DIM / 256;
    __shared__ float sbuf[4];
    int row = blockIdx.x, e = row >> 10;
    float* p = buf + (long)row * DIM;
    const float* gp = g + (long)e * DIM;
    const float* bp = beta + (long)e * DIM;
    int tid = threadIdx.x;
    float v[PT];
    float s = 0.f;
    #pragma unroll
    for (int i = 0; i < PT; ++i) { v[i] = p[tid + i * 256]; s += v[i]; }
    #pragma unroll
    for (int off = 32; off; off >>= 1) s += __shfl_down(s, off);
    if ((tid & 63) == 0) sbuf[tid >> 6] = s;
    __syncthreads();
    float mean = (sbuf[0] + sbuf[1] + sbuf[2] + sbuf[3]) / (float)DIM;
    __syncthreads();
    float vs = 0.f;
    #pragma unroll
    for (int i = 0; i < PT; ++i) { float d = v[i] - mean; vs += d * d; }
    #pragma unroll
    for (int off = 32; off; off >>= 1) vs += __shfl_down(vs, off);
    if ((tid & 63) == 0) sbuf[tid >> 6] = vs;
    __syncthreads();
    float var = (sbuf[0] + sbuf[1] + sbuf[2] + sbuf[3]) / (float)DIM;
    float rstd = rsqrtf(var + 1e-5f);
    #pragma unroll
    for (int i = 0; i < PT; ++i)
        p[tid + i * 256] = (v[i] - mean) * rstd * gp[tid + i * 256] + bp[tid + i * 256];
}

// ---------------- fused attention, bf16 in/out -----------------------------
__global__ __launch_bounds__(128) void attn_bf16(
    const unsigned short* __restrict__ qkv, unsigned short* __restrict__ o)
{
    __shared__ __align__(16) float Ks[128][64];
    __shared__ __align__(16) float Vs[128][64];
    int id = blockIdx.x;
    int hd = id & 15, b = (id >> 4) & 7, e = id >> 7;
    int tid = threadIdx.x;
    const long base = ((long)e * 1024 + b * 128) * 3072 + hd * 64;
    #pragma unroll
    for (int i = 0; i < 8; ++i) {
        int idx = i * 128 + tid;
        int row = idx >> 3, f8 = (idx & 7) * 8;
        short8v kv = *reinterpret_cast<const short8v*>(&qkv[base + (long)row * 3072 + 1024 + f8]);
        short8v vv = *reinterpret_cast<const short8v*>(&qkv[base + (long)row * 3072 + 2048 + f8]);
        #pragma unroll
        for (int j = 0; j < 8; ++j) {
            Ks[row][f8 + j] = bf2f((unsigned short)kv[j]);
            Vs[row][f8 + j] = bf2f((unsigned short)vv[j]);
        }
    }
    __syncthreads();
    float q[64];
    #pragma unroll
    for (int f = 0; f < 8; ++f) {
        short8v qv = *reinterpret_cast<const short8v*>(&qkv[base + (long)tid * 3072 + f * 8]);
        #pragma unroll
        for (int j = 0; j < 8; ++j) q[f * 8 + j] = bf2f((unsigned short)qv[j]);
    }
    float m = -__builtin_huge_valf(), l = 0.f;
    float oa[64];
    #pragma unroll
    for (int d = 0; d < 64; ++d) oa[d] = 0.f;
    for (int j = 0; j < 128; ++j) {
        float s = 0.f;
        #pragma unroll
        for (int d = 0; d < 64; ++d) s = fmaf(q[d], Ks[j][d], s);
        s *= 0.125f;
        float mn = fmaxf(m, s);
        float corr = __expf(m - mn);
        float pj = __expf(s - mn);
        l = l * corr + pj;
        #pragma unroll
        for (int d = 0; d < 64; ++d) oa[d] = oa[d] * corr + pj * Vs[j][d];
        m = mn;
    }
    float inv = 1.f / l;
    unsigned short* op = o + ((long)e * 1024 + b * 128 + tid) * 1024 + hd * 64;
    #pragma unroll
    for (int f = 0; f < 8; ++f) {
        short8v ov;
        #pragma unroll
        for (int j = 0; j < 8; ++j) ov[j] = (short)f2bf(oa[f * 8 + j] * inv);
        *reinterpret_cast<short8v*>(&op[f * 8]) = ov;
    }
}

// ---------------- LSTM step via MFMA ---------------------------------------
// pre:  bf16 [8 ed][1024 tok][4096] (x@Wi+b)
// whtf/whtb: bf16 [E][4096 col][1024 k] (transposed Wh)
// hstate: bf16 [2][8 ed][8 b][1024]; cstate: fp32 [8 ed][8 b][1024]
// memb: bf16 [E][1024 tok][2048]
__global__ __launch_bounds__(128) void lstm_step_mfma(
    const unsigned short* __restrict__ pre, const unsigned short* __restrict__ whtf,
    const unsigned short* __restrict__ whtb, unsigned short* __restrict__ hstate,
    float* __restrict__ cstate, unsigned short* __restrict__ memb, int s)
{
    __shared__ unsigned short hA[16 * 1024];      // swizzled rows of 2048B
    __shared__ float zbuf[4][8][16];
    int hc0 = blockIdx.x * 16;                    // 64 blocks
    int ed = blockIdx.y;                          // 8
    int e = ed >> 1, dir = ed & 1;
    int t = dir ? (127 - s) : s;
    const unsigned short* Wt = (dir ? whtb : whtf) + (long)e * 4096 * 1024;
    const unsigned short* hin = hstate + (long)(s & 1) * 65536 + (long)ed * 8192;
    unsigned short* hout = hstate + (long)((s & 1) ^ 1) * 65536 + (long)ed * 8192;
    int tid = threadIdx.x;
    // stage h rows 0..7 (real) + zero rows 8..15
    #pragma unroll
    for (int i = 0; i < 8; ++i) {
        int c = tid + 128 * i;
        int r = c >> 7, k8 = (c & 127) * 8;
        *reinterpret_cast<short8v*>((char*)hA + r * 2048 + ((k8 * 2) ^ ((r & 7) << 4))) =
            *reinterpret_cast<const short8v*>(hin + r * 1024 + k8);
    }
    short8v z8 = {0, 0, 0, 0, 0, 0, 0, 0};
    #pragma unroll
    for (int i = 0; i < 8; ++i) {
        int c = tid + 128 * i;
        int r = 8 + (c >> 7), k8 = (c & 127) * 8;
        *reinterpret_cast<short8v*>((char*)hA + r * 2048 + ((k8 * 2) ^ ((r & 7) << 4))) = z8;
    }
    __syncthreads();
    int w = tid >> 6, lane = tid & 63, l15 = lane & 15, l4 = lane >> 4;
    int g0 = w * 2, g1 = g0 + 1;
    const unsigned short* b0p = Wt + (long)(g0 * 1024 + hc0 + l15) * 1024 + l4 * 8;
    const unsigned short* b1p = Wt + (long)(g1 * 1024 + hc0 + l15) * 1024 + l4 * 8;
    float4v acc0 = (float4v){0.f, 0.f, 0.f, 0.f};
    float4v acc1 = (float4v){0.f, 0.f, 0.f, 0.f};
    int abase = l15 * 2048;
    int aswz = (l15 & 7) << 4;
    #pragma unroll 8
    for (int kk = 0; kk < 32; ++kk) {
        short8v a = *reinterpret_cast<const short8v*>(
            (char*)hA + abase + ((kk * 64 + l4 * 16) ^ aswz));
        short8v b0 = *reinterpret_cast<const short8v*>(b0p + kk * 32);
        short8v b1 = *reinterpret_cast<const short8v*>(b1p + kk * 32);
        acc0 = __builtin_amdgcn_mfma_f32_16x16x32_bf16(a, b0, acc0, 0, 0, 0);
        acc1 = __builtin_amdgcn_mfma_f32_16x16x32_bf16(a, b1, acc1, 0, 0, 0);
    }
    if (lane < 32) {
        #pragma unroll
        for (int r = 0; r < 4; ++r) {
            int b = l4 * 4 + r;
            zbuf[g0][b][l15] = acc0[r];
            zbuf[g1][b][l15] = acc1[r];
        }
    }
    __syncthreads();
    {
        int col = tid & 15, b = tid >> 4;         // 128 threads = 8b x 16col
        int hcol = hc0 + col;
        const unsigned short* prow = pre + ((long)ed * 1024 + b * 128 + t) * 4096;
        float zi = zbuf[0][b][col] + bf2f(prow[hcol]);
        float zf = zbuf[1][b][col] + bf2f(prow[1024 + hcol]);
        float zg = zbuf[2][b][col] + bf2f(prow[2048 + hcol]);
        float zo = zbuf[3][b][col] + bf2f(prow[3072 + hcol]);
        long ci = (long)ed * 8192 + b * 1024 + hcol;
        float c = cstate[ci];
        float ig = 1.f / (1.f + __expf(-zi));
        float fg = 1.f / (1.f + __expf(-zf));
        float gg = tanhf(zg);
        float og = 1.f / (1.f + __expf(-zo));
        c = fg * c + ig * gg;
        float h = og * tanhf(c);
        cstate[ci] = c;
        unsigned short hb = f2bf(h);
        hout[b * 1024 + hcol] = hb;
        memb[(((long)e * 8 + b) * 128 + t) * 2048 + dir * 1024 + hcol] = hb;
    }
}

// ---------------- routed combine (fp32) ------------------------------------
__global__ __launch_bounds__(256) void combine_kernel(
    const float* __restrict__ outs, const float* __restrict__ router,
    float* __restrict__ out)
{
    int idx = blockIdx.x * 256 + threadIdx.x;
    int token = idx >> 7, q = (idx & 127) * 4;
    float4 r = *reinterpret_cast<const float4*>(&router[token * 4]);
    const float* bp = outs + (long)token * 512 + q;
    float4 v0 = *reinterpret_cast<const float4*>(bp);
    float4 v1 = *reinterpret_cast<const float4*>(bp + 524288);
    float4 v2 = *reinterpret_cast<const float4*>(bp + 1048576);
    float4 v3 = *reinterpret_cast<const float4*>(bp + 1572864);
    float4 a;
    a.x = r.x * v0.x + r.y * v1.x + r.z * v2.x + r.w * v3.x;
    a.y = r.x * v0.y + r.y * v1.y + r.z * v2.y + r.w * v3.y;
    a.z = r.x * v0.z + r.y * v1.z + r.z * v2.z + r.w * v3.z;
    a.w = r.x * v0.w + r.y * v1.w + r.z * v2.w + r.w * v3.w;
    *reinterpret_cast<float4*>(&out[(long)token * 512 + q]) = a;
}

extern "C" void kernel_launch(void* const* d_in, const int* in_sizes, int n_in,
                              void* d_out, int out_size, void* d_ws, size_t ws_size,
                              hipStream_t stream)
{
    (void)in_sizes; (void)n_in; (void)out_size; (void)ws_size;
    const float* x        = (const float*)d_in[0];
    const float* router_w = (const float*)d_in[1];
    const float* router_b = (const float*)d_in[2];
    const float* enc_w1   = (const float*)d_in[3];
    const float* enc_b1   = (const float*)d_in[4];
    const float* enc_w2   = (const float*)d_in[5];
    const float* enc_b2   = (const float*)d_in[6];
    const float* enc_g    = (const float*)d_in[7];
    const float* enc_beta = (const float*)d_in[8];
    const float* aiw      = (const float*)d_in[9];
    const float* aib      = (const float*)d_in[10];
    const float* aow      = (const float*)d_in[11];
    const float* aob      = (const float*)d_in[12];
    const float* wif      = (const float*)d_in[13];
    const float* whf      = (const float*)d_in[14];
    const float* bfv      = (const float*)d_in[15];
    const float* wib      = (const float*)d_in[16];
    const float* whb      = (const float*)d_in[17];
    const float* bbv      = (const float*)d_in[18];
    const float* sw1      = (const float*)d_in[19];
    const float* sb1      = (const float*)d_in[20];
    const float* sw2      = (const float*)d_in[21];
    const float* sb2      = (const float*)d_in[22];
    const float* tw1      = (const float*)d_in[23];
    const float* tb1      = (const float*)d_in[24];
    const float* tw2      = (const float*)d_in[25];
    const float* tb2      = (const float*)d_in[26];
    const float* dw1      = (const float*)d_in[27];
    const float* db1      = (const float*)d_in[28];
    const float* dw2      = (const float*)d_in[29];
    const float* db2      = (const float*)d_in[30];
    const float* dg       = (const float*)d_in[31];
    const float* dbeta    = (const float*)d_in[32];
    float* out = (float*)d_out;

    const long m = 1024L * 1024L;
    unsigned short* U = (unsigned short*)d_ws;
    unsigned short* ew1T = U;               // 2m
    unsigned short* ew2T = U + 2 * m;       // 4m
    unsigned short* aiwT = U + 6 * m;       // 12m
    unsigned short* aowT = U + 18 * m;      // 4m
    unsigned short* wifT = U + 22 * m;      // 16m
    unsigned short* wibT = U + 38 * m;      // 16m
    unsigned short* whtf = U + 54 * m;      // 16m
    unsigned short* whtb = U + 70 * m;      // 16m
    unsigned short* sw1T = U + 86 * m;      // 8m
    unsigned short* sw2T = U + 94 * m;      // 4m
    unsigned short* tw1T = U + 98 * m;      // 8m
    unsigned short* tw2T = U + 106 * m;     // 4m
    unsigned short* dw1T = U + 110 * m;     // 4m
    unsigned short* dw2T = U + 114 * m;     // 2m
    unsigned short* xb   = U + 116 * m;     // 0.5m
    unsigned short* hbuf = xb + 524288;     // 4m
    unsigned short* t1   = hbuf + 4 * m;    // 4m
    unsigned short* t2   = t1 + 4 * m;      // 4m
    unsigned short* pre  = t2 + 4 * m;      // 32m (first 12m doubles as qkv)
    unsigned short* memb = pre + 32 * m;    // 8m
    unsigned short* hstate = memb + 8 * m;  // 131072
    float* F      = (float*)(U + 169 * m);
    float* outs   = F;                      // 2m floats
    float* router = outs + 2 * m;           // 4096
    float* cstate = router + 4096;          // 65536
    // total ~363 MB of d_ws

    hipMemsetAsync(hstate, 0, 65536 * sizeof(unsigned short), stream);
    hipMemsetAsync(cstate, 0, 65536 * sizeof(float), stream);

    // one-time conversions
    cvt_bf16_kernel<<<512, 256, 0, stream>>>(x, xb, 131072);
    transpose_bf16<<<dim3(32, 16, 4), 256, 0, stream>>>(enc_w1, ew1T, 512, 1024, 512 * 1024L, 512 * 1024L);
    transpose_bf16<<<dim3(32, 32, 4), 256, 0, stream>>>(enc_w2, ew2T, 1024, 1024, m, m);
    transpose_bf16<<<dim3(96, 32, 4), 256, 0, stream>>>(aiw, aiwT, 1024, 3072, 3 * m, 3 * m);
    transpose_bf16<<<dim3(32, 32, 4), 256, 0, stream>>>(aow, aowT, 1024, 1024, m, m);
    transpose_bf16<<<dim3(128, 32, 4), 256, 0, stream>>>(wif, wifT, 1024, 4096, 4 * m, 4 * m);
    transpose_bf16<<<dim3(128, 32, 4), 256, 0, stream>>>(wib, wibT, 1024, 4096, 4 * m, 4 * m);
    transpose_bf16<<<dim3(128, 32, 4), 256, 0, stream>>>(whf, whtf, 1024, 4096, 4 * m, 4 * m);
    transpose_bf16<<<dim3(128, 32, 4), 256, 0, stream>>>(whb, whtb, 1024, 4096, 4 * m, 4 * m);
    transpose_bf16<<<dim3(32, 64, 4), 256, 0, stream>>>(sw1, sw1T, 2048, 1024, 2 * m, 2 * m);
    transpose_bf16<<<dim3(32, 32, 4), 256, 0, stream>>>(sw2, sw2T, 1024, 1024, m, m);
    transpose_bf16<<<dim3(32, 64, 4), 256, 0, stream>>>(tw1, tw1T, 2048, 1024, 2 * m, 2 * m);
    transpose_bf16<<<dim3(32, 32, 4), 256, 0, stream>>>(tw2, tw2T, 1024, 1024, m, m);
    transpose_bf16<<<dim3(32, 32, 4), 256, 0, stream>>>(dw1, dw1T, 1024, 1024, m, m);
    transpose_bf16<<<dim3(16, 32, 4), 256, 0, stream>>>(dw2, dw2T, 1024, 512, 512 * 1024L, 512 * 1024L);

    router_kernel<<<1024, 64, 0, stream>>>(x, router_w, router_b, router);

    // encoder
    gemm_bf16<1><<<dim3(8, 8, 4), 256, 0, stream>>>(xb, ew1T, enc_b1, nullptr, t1,
        1024, 512, 0L, 512 * 1024L, 1024L, 0L, m, 1);
    gemm_bf16<1><<<dim3(8, 8, 4), 256, 0, stream>>>(t1, ew2T, enc_b2, nullptr, hbuf,
        1024, 1024, m, m, 1024L, 0L, m, 0);
    ln_bf16<1024><<<4096, 256, 0, stream>>>(hbuf, enc_g, enc_beta);
    // attention
    gemm_bf16<1><<<dim3(24, 8, 4), 256, 0, stream>>>(hbuf, aiwT, aib, nullptr, pre,
        3072, 1024, m, 3 * m, 3072L, 0L, 3 * m, 0);
    attn_bf16<<<512, 128, 0, stream>>>(pre, t1);
    gemm_bf16<1><<<dim3(8, 8, 4), 256, 0, stream>>>(t1, aowT, aob, nullptr, hbuf,
        1024, 1024, m, m, 1024L, 0L, m, 0);
    // LSTM input projections
    gemm_bf16<1><<<dim3(32, 8, 4), 256, 0, stream>>>(hbuf, wifT, bfv, nullptr, pre,
        4096, 1024, m, 4 * m, 4096L, 0L, 8 * m, 0);
    gemm_bf16<1><<<dim3(32, 8, 4), 256, 0, stream>>>(hbuf, wibT, bbv, nullptr, pre + 4 * m,
        4096, 1024, m, 4 * m, 4096L, 0L, 8 * m, 0);
    // recurrence
    for (int s = 0; s < 128; ++s)
        lstm_step_mfma<<<dim3(64, 8), 128, 0, stream>>>(pre, whtf, whtb, hstate, cstate, memb, s);
    // gates
    gemm_bf16<1><<<dim3(8, 8, 4), 256, 0, stream>>>(memb, sw1T, sb1, nullptr, t1,
        1024, 2048, 2 * m, 2 * m, 1024L, 0L, m, 1);
    gemm_bf16<1><<<dim3(8, 8, 4), 256, 0, stream>>>(t1, sw2T, sb2, nullptr, t2,
        1024, 1024, m, m, 1024L, 0L, m, 2);
    gemm_bf16<1><<<dim3(8, 8, 4), 256, 0, stream>>>(memb, tw1T, tb1, nullptr, t1,
        1024, 2048, 2 * m, 2 * m, 1024L, 0L, m, 1);
    gemm_bf16<1><<<dim3(8, 8, 4), 256, 0, stream>>>(t1, tw2T, tb2, t2, hbuf,
        1024, 1024, m, m, 1024L, m, m, 3);
    // decoder
    gemm_bf16<1><<<dim3(8, 8, 4), 256, 0, stream>>>(hbuf, dw1T, db1, nullptr, t1,
        1024, 1024, m, m, 1024L, 0L, m, 1);
    gemm_bf16<0><<<dim3(4, 8, 4), 256, 0, stream>>>(t1, dw2T, db2, nullptr, outs,
        512, 1024, m, 512 * 1024L, 512L, 0L, 512 * 1024L, 0);
    ln_kernel<512><<<4096, 256, 0, stream>>>(outs, dg, dbeta);
    combine_kernel<<<512, 256, 0, stream>>>(outs, router, out);
}